// Round 4
// baseline (4248.156 us; speedup 1.0000x reference)
//
#include <hip/hip_runtime.h>

// ---------------------------------------------------------------------------
// CSAAttention — round 4: inputs AND output are float32 (per reference).
// Round-2 pipeline (which was numerically correct); only change: final
// projection stores fp32 instead of bf16.
// Selection path (Q, K, Kc, norms, dots) in fp64; value path fp32.
// ---------------------------------------------------------------------------

#define DEVI __device__ __forceinline__

DEVI unsigned long long mapd(double x) {  // monotone fp64 -> uint64
  unsigned long long b = (unsigned long long)__double_as_longlong(x);
  return (b >> 63) ? ~b : (b | 0x8000000000000000ull);
}

// C[m][n] = sum_k A[m][k] * B[n][k] + bias[n].  Grid: (N/32, M/32).
template <typename ACCT>
__global__ __launch_bounds__(1024) void mm_abT_k(
    const float* __restrict__ A, const float* __restrict__ B,
    const float* __restrict__ bias, float* __restrict__ C,
    int Kd, int lda, int ldb, int ldc)
{
  __shared__ float As[32][33];
  __shared__ float Bs[32][33];
  const int tx = threadIdx.x, ty = threadIdx.y;
  const int m = blockIdx.y * 32 + ty;
  const int n = blockIdx.x * 32 + tx;
  ACCT acc = (ACCT)0;
  for (int k0 = 0; k0 < Kd; k0 += 32) {
    As[ty][tx] = A[(size_t)m * lda + k0 + tx];
    Bs[ty][tx] = B[(size_t)(blockIdx.x * 32 + ty) * ldb + k0 + tx];
    __syncthreads();
#pragma unroll
    for (int kk = 0; kk < 32; ++kk)
      acc += (ACCT)As[ty][kk] * (ACCT)Bs[tx][kk];
    __syncthreads();
  }
  C[(size_t)m * ldc + n] = (float)acc + bias[n];
}

// C[z][m][n] = sum_k A[m][k] * B[z][k][n] + biasRow[m].  Grid: (32, 32, Z).
template <typename ACCT>
__global__ __launch_bounds__(1024) void mm_ab_k(
    const float* __restrict__ A, const float* __restrict__ B,
    const float* __restrict__ biasRow, float* __restrict__ C,
    long long zB, long long zC)
{
  __shared__ float As[32][33];
  __shared__ float Bs[32][33];
  const int tx = threadIdx.x, ty = threadIdx.y;
  const int m = blockIdx.y * 32 + ty;
  const int n = blockIdx.x * 32 + tx;
  const float* Bz = B + (size_t)blockIdx.z * (size_t)zB;
  float* Cz = C + (size_t)blockIdx.z * (size_t)zC;
  ACCT acc = (ACCT)0;
  for (int k0 = 0; k0 < 1024; k0 += 32) {
    As[ty][tx] = A[(size_t)m * 1024 + k0 + tx];
    Bs[ty][tx] = Bz[(size_t)(k0 + ty) * 1024 + blockIdx.x * 32 + tx];
    __syncthreads();
#pragma unroll
    for (int kk = 0; kk < 32; ++kk)
      acc += (ACCT)As[ty][kk] * (ACCT)Bs[kk][tx];
    __syncthreads();
  }
  Cz[(size_t)m * 1024 + n] = (float)acc + biasRow[m];
}

// kn[b*16+h][c] = 1 / max(||Kc[b, c, h*64 : h*64+64]||, 1e-12)   (fp64)
__global__ __launch_bounds__(256) void kn_k2(const float* __restrict__ Kc,
                                             double* __restrict__ kn)
{
  int idx = (int)blockIdx.x * 256 + (int)threadIdx.x;  // [0, 32768)
  int c = idx & 1023;
  int p = idx >> 10;        // p = b*16 + h
  int b = p >> 4, h = p & 15;
  const float* row = Kc + ((size_t)(b * 1024 + c)) * 1024 + h * 64;
  double s = 0.0;
  for (int d = 0; d < 64; ++d) { double v = (double)row[d]; s += v * v; }
  kn[(size_t)p * 1024 + c] = 1.0 / fmax(sqrt(s), 1e-12);
}

// dot[z][t][c] = sum_{d<64} Q[b, t, h*64+d] * Kc[b, c, h*64+d]   (fp64)
__global__ __launch_bounds__(1024) void dot_k2(
    const float* __restrict__ Q, const float* __restrict__ Kc,
    double* __restrict__ dotp, int group_base)
{
  __shared__ float As[32][33];
  __shared__ float Bs[32][33];
  const int tx = threadIdx.x, ty = threadIdx.y;
  const int pair = group_base + (int)blockIdx.z;
  const int b = pair >> 4, h = pair & 15;
  const float* Qb = Q + (size_t)b * 1024 * 1024 + h * 64;
  const float* Kb = Kc + (size_t)b * 1024 * 1024 + h * 64;
  const int t = blockIdx.y * 32 + ty;
  const int c0 = blockIdx.x * 32;
  double acc = 0.0;
  for (int k0 = 0; k0 < 64; k0 += 32) {
    As[ty][tx] = Qb[(size_t)t * 1024 + k0 + tx];
    Bs[ty][tx] = Kb[(size_t)(c0 + ty) * 1024 + k0 + tx];
    __syncthreads();
#pragma unroll
    for (int kk = 0; kk < 32; ++kk)
      acc += (double)As[ty][kk] * (double)Bs[tx][kk];
    __syncthreads();
  }
  dotp[((size_t)blockIdx.z * 1024 + t) * 1024 + c0 + tx] = acc;
}

// One wave per (g, t) row: exact top-64 of dot[c]*kn[c] via 64 rounds of
// wave-argmax (ties -> lowest c), then softmax over dot/8, then PV gather.
__global__ __launch_bounds__(64) void topk_pv_k(
    const double* __restrict__ dotp, const double* __restrict__ kn,
    const float* __restrict__ Vc, float* __restrict__ at, int group_base)
{
  __shared__ int sSel[64];
  __shared__ float sScore[64];
  __shared__ float sW[64];

  const int lane = threadIdx.x;           // block = exactly one wave
  const int g = (int)blockIdx.x >> 10;
  const int t = (int)blockIdx.x & 1023;
  const int pair = group_base + g;
  const int b = pair >> 4, h = pair & 15;

  const double* drow = dotp + ((size_t)g * 1024 + t) * 1024;
  const double* knr  = kn + (size_t)pair * 1024;

  double dv[16];
  unsigned long long u[16];
#pragma unroll
  for (int i = 0; i < 16; ++i) {
    int c = i * 64 + lane;
    double dd = drow[c];
    dv[i] = dd;
    u[i] = mapd(dd * knr[c]);
  }

  unsigned taken = 0;
  for (int s = 0; s < 64; ++s) {
    unsigned long long bu = 0ull;
    int bc = 0x7fffffff;
#pragma unroll
    for (int i = 0; i < 16; ++i) {
      if (!((taken >> i) & 1u)) {
        int c = i * 64 + lane;
        if (u[i] > bu || (u[i] == bu && c < bc)) { bu = u[i]; bc = c; }
      }
    }
    for (int m = 1; m < 64; m <<= 1) {
      unsigned long long ou = __shfl_xor(bu, m);
      int oc = __shfl_xor(bc, m);
      if (ou > bu || (ou == bu && oc < bc)) { bu = ou; bc = oc; }
    }
    if ((bc & 63) == lane) {            // exactly one owner lane
      taken |= 1u << (bc >> 6);
      sSel[s] = bc;
      sScore[s] = (float)dv[bc >> 6];
    }
  }
  __syncthreads();

  float sc = sScore[lane] * 0.125f;
  float mx = sc;
  for (int m = 1; m < 64; m <<= 1) mx = fmaxf(mx, __shfl_xor(mx, m));
  float w = expf(sc - mx);
  float sw = w;
  for (int m = 1; m < 64; m <<= 1) sw += __shfl_xor(sw, m);
  sW[lane] = w / sw;
  __syncthreads();

  const float* Vb = Vc + (size_t)b * 1024 * 1024 + h * 64 + lane;
  float acc = 0.f;
  for (int k = 0; k < 64; ++k)
    acc = fmaf(sW[k], Vb[(size_t)sSel[k] * 1024], acc);
  at[((size_t)(b * 1024 + t)) * 1024 + h * 64 + lane] = acc;
}

// ---------------------------------------------------------------------------
extern "C" void kernel_launch(void* const* d_in, const int* in_sizes, int n_in,
                              void* d_out, int out_size, void* d_ws, size_t ws_size,
                              hipStream_t stream)
{
  const float* x  = (const float*)d_in[0];
  const float* Wq = (const float*)d_in[1];
  const float* bq = (const float*)d_in[2];
  const float* Wk = (const float*)d_in[3];
  const float* bk = (const float*)d_in[4];
  const float* Wv = (const float*)d_in[5];
  const float* bv = (const float*)d_in[6];
  const float* Wo = (const float*)d_in[7];
  const float* bo = (const float*)d_in[8];
  const float* Wc = (const float*)d_in[9];
  const float* bc = (const float*)d_in[10];
  float* out = (float*)d_out;            // fp32, per reference output dtype

  const size_t NE = (size_t)2048 * 1024;  // elements per 2048x1024 fp32 plane
  float* Q  = (float*)d_ws;      // [0,  8 MiB)
  float* Kf = Q + NE;            // [8,  16)
  float* Vf = Kf + NE;           // [16, 24)
  float* Kc = Vf + NE;           // [24, 32)
  float* Vc = Kc + NE;           // [32, 40)
  float* at = Vc + NE;           // [40, 48)
  double* kn = (double*)(at + NE);          // 32768 doubles
  double* dotw = (double*)Kf;    // dot planes alias dead Kf+Vf (16 MiB, G=2)

  const size_t fixedB = 6 * NE * 4 + 32768 * 8;
  if (ws_size < fixedB) return;  // ws too small: output stays zero (diagnostic)

  const dim3 b1024(32, 32, 1);
  const long long M1 = 1024 * 1024;

  // Projections: P = x @ W^T + b.  (2048 x 1024) x (1024 x 1024)^T
  mm_abT_k<double><<<dim3(32, 64, 1), b1024, 0, stream>>>(
      x, Wq, bq, Q, 1024, 1024, 1024, 1024);
  mm_abT_k<double><<<dim3(32, 64, 1), b1024, 0, stream>>>(
      x, Wk, bk, Kf, 1024, 1024, 1024, 1024);
  mm_abT_k<float><<<dim3(32, 64, 1), b1024, 0, stream>>>(
      x, Wv, bv, Vf, 1024, 1024, 1024, 1024);

  // Compress (per batch z): Kc[z] = Wc @ Kf[z] + bc (bias per output row c)
  mm_ab_k<double><<<dim3(32, 32, 2), b1024, 0, stream>>>(Wc, Kf, bc, Kc, M1, M1);
  mm_ab_k<float><<<dim3(32, 32, 2), b1024, 0, stream>>>(Wc, Vf, bc, Vc, M1, M1);

  // Inverse norms of Kc head-slices (fp64 ordering key)
  kn_k2<<<dim3(128), dim3(256), 0, stream>>>(Kc, kn);

  // Per (b,h) pair group of 2: fp64 dot plane, then fused topk+softmax+PV
  for (int gb = 0; gb < 32; gb += 2) {
    dot_k2<<<dim3(32, 32, 2), b1024, 0, stream>>>(Q, Kc, dotw, gb);
    topk_pv_k<<<dim3(2048), dim3(64), 0, stream>>>(dotw, kn, Vc, at, gb);
  }

  // Output projection (fp32): out = at @ Wo^T + bo
  mm_abT_k<float><<<dim3(32, 64, 1), b1024, 0, stream>>>(
      at, Wo, bo, out, 1024, 1024, 1024, 1024);
}

// Round 5
// 1060.172 us; speedup vs baseline: 4.0070x; 4.0070x over previous
//
#include <hip/hip_runtime.h>
#include <type_traits>

// ---------------------------------------------------------------------------
// CSAAttention — round 5: fast validated components.
//   fp32 inputs/outputs. Selection path (Q, K, Kc via fp64 acc -> fp32 store;
//   norms/dots fp64 on fp32 values) EXACTLY matches round-4's rounding
//   contract. Value path fp32. 64x64-tile GEMMs + radix top-64.
// ---------------------------------------------------------------------------

#define DEVI __device__ __forceinline__

constexpr int Tn = 1024;
constexpr int Cn = 1024;
constexpr int Hn = 16;

DEVI int wsumi(int v)   { for (int m = 1; m < 64; m <<= 1) v += __shfl_xor(v, m); return v; }
DEVI int wmini(int v)   { for (int m = 1; m < 64; m <<= 1) { int o = __shfl_xor(v, m); v = o < v ? o : v; } return v; }
DEVI float wfmax(float v){ for (int m = 1; m < 64; m <<= 1) v = fmaxf(v, __shfl_xor(v, m)); return v; }
DEVI float wfsum(float v){ for (int m = 1; m < 64; m <<= 1) v += __shfl_xor(v, m); return v; }

DEVI unsigned long long mapd(double x) {  // monotone fp64 -> uint64
  unsigned long long b = (unsigned long long)__double_as_longlong(x);
  return (b >> 63) ? ~b : (b | 0x8000000000000000ull);
}

// ---------------------------------------------------------------------------
// Tiled GEMM: C = A * op(B) (+ bias). Tile 64x64, 256 threads, 4x4 micro,
// BK=16. BTRANS: C=A*B^T. BIASMODE: 0 none, 1 bias[n], 2 bias[m].
// SIM: per-z (b,h) head-slices of A=Q, B=Kc; C = fp64 dot plane.
// ---------------------------------------------------------------------------
template <typename OUTT, typename ACCT, bool BTRANS, int BIASMODE, bool SIM>
__global__ __launch_bounds__(256) void gemm_k(
    const float* __restrict__ A, const float* __restrict__ B,
    const float* __restrict__ bias, OUTT* __restrict__ C,
    int Kd, int lda, int ldb, int ldc,
    long long zA, long long zB, long long zC, int group_base)
{
  __shared__ float As[16][68];
  __shared__ float Bs[16][68];

  size_t offA, offB, offC;
  if (SIM) {
    int pair = group_base + (int)blockIdx.z;
    int bb = pair >> 4, hh = pair & 15;
    offA = ((size_t)bb * Tn) * (size_t)lda + (size_t)hh * 64;
    offB = ((size_t)bb * Cn) * (size_t)ldb + (size_t)hh * 64;
    offC = (size_t)blockIdx.z * (size_t)Tn * (size_t)ldc;
  } else {
    offA = (size_t)blockIdx.z * (size_t)zA;
    offB = (size_t)blockIdx.z * (size_t)zB;
    offC = (size_t)blockIdx.z * (size_t)zC;
  }
  const float* Ab = A + offA;
  const float* Bb = B + offB;
  OUTT* Cb = C + offC;

  const int tid = threadIdx.x;
  const int tx = tid & 15, ty = tid >> 4;
  const int m0 = blockIdx.y * 64, n0 = blockIdx.x * 64;

  ACCT acc[4][4];
#pragma unroll
  for (int i = 0; i < 4; ++i)
#pragma unroll
    for (int j = 0; j < 4; ++j) acc[i][j] = (ACCT)0;

  for (int k0 = 0; k0 < Kd; k0 += 16) {
    {  // stage A: 64 rows x 16 k
      int m = tid >> 2, kf = tid & 3;
      float4 a = *(const float4*)(Ab + (size_t)(m0 + m) * lda + k0 + 4 * kf);
      As[4 * kf + 0][m] = a.x; As[4 * kf + 1][m] = a.y;
      As[4 * kf + 2][m] = a.z; As[4 * kf + 3][m] = a.w;
    }
    if (BTRANS) {
      int n = tid >> 2, kf = tid & 3;
      float4 b = *(const float4*)(Bb + (size_t)(n0 + n) * ldb + k0 + 4 * kf);
      Bs[4 * kf + 0][n] = b.x; Bs[4 * kf + 1][n] = b.y;
      Bs[4 * kf + 2][n] = b.z; Bs[4 * kf + 3][n] = b.w;
    } else {
      int k = tid >> 4, nf = tid & 15;
      float4 b = *(const float4*)(Bb + (size_t)(k0 + k) * ldb + n0 + 4 * nf);
      *(float4*)&Bs[k][4 * nf] = b;
    }
    __syncthreads();
#pragma unroll
    for (int k = 0; k < 16; ++k) {
      float4 a4 = *(const float4*)&As[k][4 * ty];
      float4 b4 = *(const float4*)&Bs[k][4 * tx];
      float av[4] = {a4.x, a4.y, a4.z, a4.w};
      float bv[4] = {b4.x, b4.y, b4.z, b4.w};
#pragma unroll
      for (int i = 0; i < 4; ++i)
#pragma unroll
        for (int j = 0; j < 4; ++j)
          acc[i][j] += (ACCT)av[i] * (ACCT)bv[j];
    }
    __syncthreads();
  }

  if constexpr (std::is_same<OUTT, double>::value) {
#pragma unroll
    for (int i = 0; i < 4; ++i) {
      size_t m = (size_t)(m0 + 4 * ty + i);
      double* p = (double*)Cb + m * ldc + n0 + 4 * tx;
      p[0] = (double)acc[i][0]; p[1] = (double)acc[i][1];
      p[2] = (double)acc[i][2]; p[3] = (double)acc[i][3];
    }
  } else {
    float cbv[4] = {0.f, 0.f, 0.f, 0.f};
    if (BIASMODE == 1) {
      float4 b4 = *(const float4*)(bias + n0 + 4 * tx);
      cbv[0] = b4.x; cbv[1] = b4.y; cbv[2] = b4.z; cbv[3] = b4.w;
    }
#pragma unroll
    for (int i = 0; i < 4; ++i) {
      int m = m0 + 4 * ty + i;
      float rb = (BIASMODE == 2) ? bias[m] : 0.f;
      float4 s;
      s.x = (float)acc[i][0] + cbv[0] + rb;
      s.y = (float)acc[i][1] + cbv[1] + rb;
      s.z = (float)acc[i][2] + cbv[2] + rb;
      s.w = (float)acc[i][3] + cbv[3] + rb;
      *(float4*)((float*)Cb + (size_t)m * ldc + n0 + 4 * tx) = s;
    }
  }
}

// kn[b*16+h][c] = 1 / max(||Kc[b, c, h*64 : +64]||, 1e-12)   (fp64)
__global__ __launch_bounds__(256) void kn_k2(const float* __restrict__ Kc,
                                             double* __restrict__ kn)
{
  int idx = (int)blockIdx.x * 256 + (int)threadIdx.x;  // [0, 32768)
  int c = idx & 1023;
  int p = idx >> 10;        // p = b*16 + h
  int b = p >> 4, h = p & 15;
  const float* row = Kc + ((size_t)(b * 1024 + c)) * 1024 + h * 64;
  double s = 0.0;
  for (int d = 0; d < 64; ++d) { double v = (double)row[d]; s += v * v; }
  kn[(size_t)p * 1024 + c] = 1.0 / fmax(sqrt(s), 1e-12);
}

// ---------------------------------------------------------------------------
// Fused exact top-64 + softmax + PV. 4 rows / 256-thread block, 1 wave/row.
// keys = dot*kn (fp64), 16/lane in regs; 64th-largest via hi/lo binary
// search on monotone uint64; ties -> ascending c. Softmax over dot/8.
// ---------------------------------------------------------------------------
__global__ __launch_bounds__(256) void topk_attn_k(
    const double* __restrict__ dotb, const double* __restrict__ kn,
    const float* __restrict__ Vc, float* __restrict__ attnout, int group_base)
{
  __shared__ int sC[4][64];
  __shared__ float sD[4][64];

  const int lane = threadIdx.x & 63, wv = threadIdx.x >> 6;
  const int g = (int)blockIdx.x >> 8;
  const int t = ((int)blockIdx.x & 255) * 4 + wv;
  const int pair = group_base + g;
  const int bb = pair >> 4, hh = pair & 15;

  const double* drow = dotb + ((size_t)g * Tn + t) * (size_t)Cn;
  const double* knr  = kn + ((size_t)(bb * Hn + hh)) * Cn;

  double dv[16];
  unsigned long long u[16];
#pragma unroll
  for (int j = 0; j < 8; ++j) {
    double2 dd = *(const double2*)(drow + j * 128 + 2 * lane);
    double2 kk = *(const double2*)(knr  + j * 128 + 2 * lane);
    dv[2 * j] = dd.x; dv[2 * j + 1] = dd.y;
    u[2 * j]     = mapd(dd.x * kk.x);
    u[2 * j + 1] = mapd(dd.y * kk.y);
  }
  unsigned hi[16];
#pragma unroll
  for (int i = 0; i < 16; ++i) hi[i] = (unsigned)(u[i] >> 32);

  // 64th-largest key: binary search hi word, then lo word within hi==TH
  unsigned TH = 0;
  for (int bit = 31; bit >= 0; --bit) {
    unsigned Tc = TH | (1u << bit);
    int c = 0;
#pragma unroll
    for (int i = 0; i < 16; ++i) c += (hi[i] >= Tc);
    if (wsumi(c) >= 64) TH = Tc;
  }
  int mhi = 0;
#pragma unroll
  for (int i = 0; i < 16; ++i) mhi += (hi[i] > TH);
  mhi = wsumi(mhi);
  const int need1 = 64 - mhi;
  unsigned TL = 0;
  for (int bit = 31; bit >= 0; --bit) {
    unsigned Tc = TL | (1u << bit);
    int c = 0;
#pragma unroll
    for (int i = 0; i < 16; ++i) c += (hi[i] == TH && (unsigned)u[i] >= Tc);
    if (wsumi(c) >= need1) TL = Tc;
  }
  const unsigned long long V64 = ((unsigned long long)TH << 32) | TL;

  // emit strictly-greater
  int base = 0;
#pragma unroll
  for (int i = 0; i < 16; ++i) {
    const int cix = 128 * (i >> 1) + 2 * lane + (i & 1);
    bool sel = (u[i] > V64);
    unsigned long long mk = __ballot(sel);
    if (sel) {
      int r = __popcll(mk & ((1ull << lane) - 1ull));
      sC[wv][base + r] = cix;
      sD[wv][base + r] = (float)dv[i];
    }
    base += __popcll(mk);
  }
  // ties (== V64): lowest c first, exactly need of them
  const int need = 64 - base;
  unsigned taken = 0;
  for (int r = 0; r < need; ++r) {
    int mn = 0x7fffffff;
#pragma unroll
    for (int i = 0; i < 16; ++i) {
      int cix = 128 * (i >> 1) + 2 * lane + (i & 1);
      if (u[i] == V64 && !((taken >> i) & 1u)) mn = mn < cix ? mn : cix;
    }
    mn = wmini(mn);
#pragma unroll
    for (int i = 0; i < 16; ++i) {
      int cix = 128 * (i >> 1) + 2 * lane + (i & 1);
      if (u[i] == V64 && !((taken >> i) & 1u) && cix == mn) {
        taken |= 1u << i;
        sC[wv][base + r] = mn;
        sD[wv][base + r] = (float)dv[i];
      }
    }
  }
  __syncthreads();

  // softmax over selected scores (= dot/8), then PV gather
  int ck = sC[wv][lane];
  float sc = sD[wv][lane] * 0.125f;
  float mx = wfmax(sc);
  float w = expf(sc - mx);
  float sw = wfsum(w);
  w /= sw;

  const float* Vb = Vc + (size_t)bb * ((size_t)Cn * 1024) + hh * 64 + lane;
  float acc = 0.f;
#pragma unroll 4
  for (int k = 0; k < 64; ++k) {
    int c = __shfl(ck, k);
    float wk = __shfl(w, k);
    acc = fmaf(wk, Vb[(size_t)c * 1024], acc);
  }
  attnout[((size_t)(bb * Tn + t)) * 1024 + hh * 64 + lane] = acc;
}

// ---------------------------------------------------------------------------
extern "C" void kernel_launch(void* const* d_in, const int* in_sizes, int n_in,
                              void* d_out, int out_size, void* d_ws, size_t ws_size,
                              hipStream_t stream)
{
  const float* x  = (const float*)d_in[0];
  const float* Wq = (const float*)d_in[1];
  const float* bq = (const float*)d_in[2];
  const float* Wk = (const float*)d_in[3];
  const float* bk = (const float*)d_in[4];
  const float* Wv = (const float*)d_in[5];
  const float* bv = (const float*)d_in[6];
  const float* Wo = (const float*)d_in[7];
  const float* bo = (const float*)d_in[8];
  const float* Wc = (const float*)d_in[9];
  const float* bc = (const float*)d_in[10];
  float* out = (float*)d_out;

  const size_t NE = (size_t)2048 * 1024;
  float* Q  = (float*)d_ws;
  float* Kf = Q + NE;
  float* Vf = Kf + NE;
  float* Kc = Vf + NE;
  float* Vc = Kc + NE;
  float* at = Vc + NE;
  double* kn = (double*)(at + NE);
  double* tail = kn + 32768;

  const size_t fixedB = 6 * NE * 4 + 32768 * 8;
  const size_t dotPairB = (size_t)Tn * Cn * 8;  // 8 MB per (b,h) pair
  if (ws_size < fixedB) return;

  size_t rem = ws_size - fixedB;
  double* dotp; int G;
  if      (rem >= 8 * dotPairB) { G = 8; dotp = tail; }
  else if (rem >= 4 * dotPairB) { G = 4; dotp = tail; }
  else if (rem >= 2 * dotPairB) { G = 2; dotp = tail; }
  else { G = 2; dotp = (double*)Kf; }  // Kf+Vf dead by then (16 MB)

  dim3 blk(256, 1, 1);
  const long long M1 = 1024 * 1024;

  // Projections: P = x @ W^T + b  (fp64 acc for Q,K; fp32 for V)
  gemm_k<float, double, true, 1, false><<<dim3(16, 32, 1), blk, 0, stream>>>(
      x, Wq, bq, Q, 1024, 1024, 1024, 1024, 0, 0, 0, 0);
  gemm_k<float, double, true, 1, false><<<dim3(16, 32, 1), blk, 0, stream>>>(
      x, Wk, bk, Kf, 1024, 1024, 1024, 1024, 0, 0, 0, 0);
  gemm_k<float, float, true, 1, false><<<dim3(16, 32, 1), blk, 0, stream>>>(
      x, Wv, bv, Vf, 1024, 1024, 1024, 1024, 0, 0, 0, 0);

  // Compress per batch z: Kc[z] = Wc @ Kf[z] + bc (row bias)
  gemm_k<float, double, false, 2, false><<<dim3(16, 16, 2), blk, 0, stream>>>(
      Wc, Kf, bc, Kc, 1024, 1024, 1024, 1024, 0, M1, M1, 0);
  gemm_k<float, float, false, 2, false><<<dim3(16, 16, 2), blk, 0, stream>>>(
      Wc, Vf, bc, Vc, 1024, 1024, 1024, 1024, 0, M1, M1, 0);

  kn_k2<<<dim3(128), dim3(256), 0, stream>>>(Kc, kn);

  // Per (b,h) group: fp64 dot plane, then fused topk+softmax+PV
  for (int gb = 0; gb < 32; gb += G) {
    gemm_k<double, double, true, 0, true><<<dim3(16, 16, G), blk, 0, stream>>>(
        Q, Kc, nullptr, dotp, 64, 1024, 1024, 1024, 0, 0, 0, gb);
    topk_attn_k<<<dim3(256 * G), blk, 0, stream>>>(dotp, kn, Vc, at, gb);
  }

  // Output projection (fp32): out = at @ Wo^T + bo
  gemm_k<float, float, true, 1, false><<<dim3(16, 32, 1), blk, 0, stream>>>(
      at, Wo, bo, out, 1024, 1024, 1024, 1024, 0, 0, 0, 0);
}